// Round 1
// baseline (643.502 us; speedup 1.0000x reference)
//
#include <hip/hip_runtime.h>
#include <cstdint>

typedef __bf16 bf16_t;
typedef __attribute__((ext_vector_type(8))) __bf16 bf16x8;
typedef __attribute__((ext_vector_type(4))) float f32x4;

#define MC_EPS 1e-8f

__device__ __forceinline__ void async_ld16(const bf16_t* g, bf16_t* l) {
  __builtin_amdgcn_global_load_lds(
      (const __attribute__((address_space(1))) void*)g,
      (__attribute__((address_space(3))) void*)l, 16, 0, 0);
}

// s[b][ci] = dot(w[b,:], affine_w[ci,:]) + affine_b[ci] + 1
__global__ void s_kernel(const float* __restrict__ w, const float* __restrict__ aw,
                         const float* __restrict__ ab, float* __restrict__ s) {
  int b = blockIdx.x >> 9, ci = blockIdx.x & 511, lane = threadIdx.x;
  const float* wr = w + (b << 9);
  const float* ar = aw + (ci << 9);
  float acc = 0.f;
  for (int l = lane; l < 512; l += 64) acc += wr[l] * ar[l];
  for (int off = 32; off; off >>= 1) acc += __shfl_down(acc, off, 64);
  if (lane == 0) s[(b << 9) + ci] = acc + ab[ci] + 1.0f;
}

// wsq[co][ci] = sum_t weight[co][ci][t]^2
__global__ void wsq_kernel(const float* __restrict__ wgt, float* __restrict__ wsq) {
  int idx = blockIdx.x * 256 + threadIdx.x;  // < 262144
  const float* p = wgt + idx * 9;
  float a = 0.f;
#pragma unroll
  for (int j = 0; j < 9; ++j) a += p[j] * p[j];
  wsq[idx] = a;
}

// d[b][co] = rsqrt(sum_ci wsq[co][ci] * s[b][ci]^2 + eps)
__global__ void d_kernel(const float* __restrict__ wsq, const float* __restrict__ s,
                         float* __restrict__ d) {
  int b = blockIdx.x >> 9, co = blockIdx.x & 511, lane = threadIdx.x;
  const float* wr = wsq + (co << 9);
  const float* sr = s + (b << 9);
  float acc = 0.f;
  for (int l = lane; l < 512; l += 64) { float sv = sr[l]; acc += wr[l] * sv * sv; }
  for (int off = 32; off; off >>= 1) acc += __shfl_down(acc, off, 64);
  if (lane == 0) d[(b << 9) + co] = rsqrtf(acc + MC_EPS);
}

// w_t[t][co][ci] = bf16(weight[co][ci][t])   (ci-contiguous B operand)
__global__ void wt_kernel(const float* __restrict__ wgt, bf16_t* __restrict__ w_t) {
  int o = blockIdx.x * 256 + threadIdx.x;   // < 9*262144
  int t = o >> 18;
  int rem = o & 262143;
  int co = rem >> 9, ci = rem & 511;
  w_t[o] = (bf16_t)wgt[(((co << 9) + ci) * 9) + t];
}

// x_pad[b][h+1][w+1][ci] = bf16(x[b][ci][h][w] * s[b][ci])  (NHWC, 1-px halo)
__global__ void xmod_kernel(const float* __restrict__ x, const float* __restrict__ s,
                            bf16_t* __restrict__ xp) {
  int b = blockIdx.x >> 6, h = blockIdx.x & 63;
  int tid = threadIdx.x;
  __shared__ __align__(16) bf16_t tile[64 * 130];
  for (int c0 = 0; c0 < 512; c0 += 128) {
    if (c0) __syncthreads();
    int w4 = (tid & 15) << 2;   // 0..60
    int cl = tid >> 4;          // 0..15
#pragma unroll
    for (int r = 0; r < 8; ++r) {
      int ci = cl + (r << 4);   // 0..127
      const float4 v = *(const float4*)&x[(size_t)(((b << 9) + c0 + ci) << 12) + (h << 6) + w4];
      float sv = s[(b << 9) + c0 + ci];
      tile[(w4 + 0) * 130 + ci] = (bf16_t)(v.x * sv);
      tile[(w4 + 1) * 130 + ci] = (bf16_t)(v.y * sv);
      tile[(w4 + 2) * 130 + ci] = (bf16_t)(v.z * sv);
      tile[(w4 + 3) * 130 + ci] = (bf16_t)(v.w * sv);
    }
    __syncthreads();
#pragma unroll
    for (int it = 0; it < 4; ++it) {
      int i = tid + it * 256;       // < 1024
      int w = i >> 4, cg = i & 15;  // 8 ci per chunk
      const uint32_t* tp = (const uint32_t*)&tile[w * 130 + (cg << 3)];
      uint4 v = { tp[0], tp[1], tp[2], tp[3] };
      *(uint4*)&xp[((size_t)(b * 66 + h + 1) * 66 + (w + 1)) * 512 + c0 + (cg << 3)] = v;
    }
  }
}

// Implicit-GEMM conv: D[(b,h,w)][co] = sum_{tap,ci} x_pad * w_t, scaled by d[b][co].
// 128 pixels (2 rows) x 128 co per block, 4 waves (2x2), 16x16x32 bf16 MFMA, BK=32.
__global__ __launch_bounds__(256) void conv_kernel(
    const bf16_t* __restrict__ xp, const bf16_t* __restrict__ w_t,
    const float* __restrict__ d, float* __restrict__ out) {
  __shared__ __align__(16) bf16_t smem[8192];   // As[128][32] | Bs[128][32]
  const int tid = threadIdx.x, lane = tid & 63;
  const int mb = blockIdx.x >> 2, nb = blockIdx.x & 3;
  const int b = mb >> 5;
  const int h0 = (mb & 31) << 1;
  const int n0 = nb << 7;
  const int wv = tid >> 6, wm = wv >> 1, wn = wv & 1;
  const int quad = lane >> 4, lr = lane & 15;

  f32x4 acc[4][4];
#pragma unroll
  for (int i = 0; i < 4; ++i)
#pragma unroll
    for (int j = 0; j < 4; ++j) acc[i][j] = (f32x4){0.f, 0.f, 0.f, 0.f};

  for (int t = 0; t < 9; ++t) {
    const int kh = t / 3, kw = t % 3;
    for (int ci0 = 0; ci0 < 512; ci0 += 32) {
      __syncthreads();
      // stage A: 128 pixels x 32 ci (8 KB), per-lane global addr -> wave-uniform LDS
#pragma unroll
      for (int it = 0; it < 2; ++it) {
        int i = tid + (it << 8);          // [0,512)
        int pix = i >> 2;                 // [0,128)
        int kk = (i & 3) << 3;            // 0,8,16,24
        int hp = h0 + (pix >> 6) + kh;    // [0,66)
        int wp = (pix & 63) + kw;         // [0,66)
        const bf16_t* gp = xp + (((size_t)(b * 66 + hp) * 66 + wp) << 9) + ci0 + kk;
        async_ld16(gp, &smem[(i & ~63) << 3]);
      }
      // stage B: 128 co x 32 ci (8 KB)
#pragma unroll
      for (int it = 0; it < 2; ++it) {
        int i = tid + (it << 8);
        int n = i >> 2, kk = (i & 3) << 3;
        const bf16_t* gp = w_t + (((size_t)((t << 9) + n0 + n)) << 9) + ci0 + kk;
        async_ld16(gp, &smem[4096 + ((i & ~63) << 3)]);
      }
      __syncthreads();
      bf16x8 af[4], bfr[4];
#pragma unroll
      for (int mt = 0; mt < 4; ++mt)
        af[mt] = *(const bf16x8*)&smem[(((wm << 6) + (mt << 4) + lr) << 5) + (quad << 3)];
#pragma unroll
      for (int nt = 0; nt < 4; ++nt)
        bfr[nt] = *(const bf16x8*)&smem[4096 + (((wn << 6) + (nt << 4) + lr) << 5) + (quad << 3)];
#pragma unroll
      for (int mt = 0; mt < 4; ++mt)
#pragma unroll
        for (int nt = 0; nt < 4; ++nt)
          acc[mt][nt] = __builtin_amdgcn_mfma_f32_16x16x32_bf16(af[mt], bfr[nt], acc[mt][nt], 0, 0, 0);
    }
  }

  // epilogue: out[b][co][h][w] = acc * d[b][co]
#pragma unroll
  for (int nt = 0; nt < 4; ++nt) {
    const int n = n0 + (wn << 6) + (nt << 4) + lr;
    const float dv = d[(b << 9) + n];
#pragma unroll
    for (int mt = 0; mt < 4; ++mt) {
#pragma unroll
      for (int r = 0; r < 4; ++r) {
        int m = (wm << 6) + (mt << 4) + (quad << 2) + r;   // pixel in tile
        int h = h0 + (m >> 6), w = m & 63;
        out[((size_t)((b << 9) + n) << 12) + (h << 6) + w] = acc[mt][nt][r] * dv;
      }
    }
  }
}

extern "C" void kernel_launch(void* const* d_in, const int* in_sizes, int n_in,
                              void* d_out, int out_size, void* d_ws, size_t ws_size,
                              hipStream_t stream) {
  const float* x      = (const float*)d_in[0];   // [16,512,64,64]
  const float* w      = (const float*)d_in[1];   // [16,512]
  const float* weight = (const float*)d_in[2];   // [512,512,3,3]
  const float* aw     = (const float*)d_in[3];   // [512,512]
  const float* ab     = (const float*)d_in[4];   // [512]
  float* out = (float*)d_out;

  char* ws = (char*)d_ws;
  const size_t XP_BYTES  = (size_t)16 * 66 * 66 * 512 * 2;  // 71,368,704
  const size_t WT_BYTES  = (size_t)9 * 512 * 512 * 2;       //  4,718,592
  bf16_t* xp   = (bf16_t*)ws;
  bf16_t* w_t  = (bf16_t*)(ws + XP_BYTES);
  float*  s    = (float*)(ws + XP_BYTES + WT_BYTES);
  float*  wsq  = (float*)(ws + XP_BYTES + WT_BYTES + 32768);
  float*  dbuf = (float*)(ws + XP_BYTES + WT_BYTES + 32768 + 1048576);

  hipMemsetAsync(xp, 0, XP_BYTES, stream);                  // zero halo (whole buf)
  s_kernel<<<8192, 64, 0, stream>>>(w, aw, ab, s);
  wsq_kernel<<<1024, 256, 0, stream>>>(weight, wsq);
  d_kernel<<<8192, 64, 0, stream>>>(wsq, s, dbuf);
  wt_kernel<<<9216, 256, 0, stream>>>(weight, w_t);
  xmod_kernel<<<1024, 256, 0, stream>>>(x, s, xp);
  conv_kernel<<<2048, 256, 0, stream>>>(xp, w_t, dbuf, out);
}

// Round 2
// 604.487 us; speedup vs baseline: 1.0645x; 1.0645x over previous
//
#include <hip/hip_runtime.h>
#include <cstdint>

typedef __bf16 bf16_t;
typedef __attribute__((ext_vector_type(8))) __bf16 bf16x8;
typedef __attribute__((ext_vector_type(4))) float f32x4;

#define MC_EPS 1e-8f

__device__ __forceinline__ void async_ld16(const bf16_t* g, bf16_t* l) {
  __builtin_amdgcn_global_load_lds(
      (const __attribute__((address_space(1))) void*)g,
      (__attribute__((address_space(3))) void*)l, 16, 0, 0);
}

// s[b][ci] = dot(w[b,:], affine_w[ci,:]) + affine_b[ci] + 1
__global__ void s_kernel(const float* __restrict__ w, const float* __restrict__ aw,
                         const float* __restrict__ ab, float* __restrict__ s) {
  int b = blockIdx.x >> 9, ci = blockIdx.x & 511, lane = threadIdx.x;
  const float* wr = w + (b << 9);
  const float* ar = aw + (ci << 9);
  float acc = 0.f;
  for (int l = lane; l < 512; l += 64) acc += wr[l] * ar[l];
  for (int off = 32; off; off >>= 1) acc += __shfl_down(acc, off, 64);
  if (lane == 0) s[(b << 9) + ci] = acc + ab[ci] + 1.0f;
}

// fused: wsq[co][ci] = sum_t w^2 ; w_t[t][co][ci] = bf16(w)  (one pass over weight)
__global__ void prep_w_kernel(const float* __restrict__ wgt, float* __restrict__ wsq,
                              bf16_t* __restrict__ w_t) {
  int idx = blockIdx.x * 256 + threadIdx.x;  // co*512+ci, < 262144
  const float* p = wgt + (size_t)idx * 9;
  float v[9];
  float a = 0.f;
#pragma unroll
  for (int j = 0; j < 9; ++j) { v[j] = p[j]; a += v[j] * v[j]; }
  wsq[idx] = a;
#pragma unroll
  for (int j = 0; j < 9; ++j) w_t[((size_t)j << 18) + idx] = (bf16_t)v[j];
}

// d[b][co] = rsqrt(sum_ci wsq[co][ci] * s[b][ci]^2 + eps)
__global__ void d_kernel(const float* __restrict__ wsq, const float* __restrict__ s,
                         float* __restrict__ d) {
  int b = blockIdx.x >> 9, co = blockIdx.x & 511, lane = threadIdx.x;
  const float* wr = wsq + (co << 9);
  const float* sr = s + (b << 9);
  float acc = 0.f;
  for (int l = lane; l < 512; l += 64) { float sv = sr[l]; acc += wr[l] * sv * sv; }
  for (int off = 32; off; off >>= 1) acc += __shfl_down(acc, off, 64);
  if (lane == 0) d[(b << 9) + co] = rsqrtf(acc + MC_EPS);
}

// zero only the 1-px halo border of x_pad (4.3 MB instead of 71 MB memset)
__global__ void halo_kernel(bf16_t* __restrict__ xp) {
  int gid = blockIdx.x * 256 + threadIdx.x;  // 16*260*64 = 266240 threads
  if (gid >= 16 * 260 * 64) return;
  int cg = gid & 63;
  int p = (gid >> 6) % 260;
  int b = (gid >> 6) / 260;
  int h, w;
  if (p < 66)       { h = 0;       w = p; }
  else if (p < 132) { h = 65;      w = p - 66; }
  else if (p < 196) { h = p - 131; w = 0; }
  else              { h = p - 195; w = 65; }
  uint4 z = {0u, 0u, 0u, 0u};
  *(uint4*)&xp[((size_t)(b * 66 + h) * 66 + w) * 512 + (cg << 3)] = z;
}

// x_pad[b][h+1][w+1][ci] = bf16(x[b][ci][h][w] * s[b][ci])  (NHWC, 1-px halo)
__global__ void xmod_kernel(const float* __restrict__ x, const float* __restrict__ s,
                            bf16_t* __restrict__ xp) {
  int b = blockIdx.x >> 6, h = blockIdx.x & 63;
  int tid = threadIdx.x;
  __shared__ __align__(16) bf16_t tile[64 * 130];
  for (int c0 = 0; c0 < 512; c0 += 128) {
    if (c0) __syncthreads();
    int w4 = (tid & 15) << 2;   // 0..60
    int cl = tid >> 4;          // 0..15
#pragma unroll
    for (int r = 0; r < 8; ++r) {
      int ci = cl + (r << 4);   // 0..127
      const float4 v = *(const float4*)&x[(size_t)(((b << 9) + c0 + ci) << 12) + (h << 6) + w4];
      float sv = s[(b << 9) + c0 + ci];
      tile[(w4 + 0) * 130 + ci] = (bf16_t)(v.x * sv);
      tile[(w4 + 1) * 130 + ci] = (bf16_t)(v.y * sv);
      tile[(w4 + 2) * 130 + ci] = (bf16_t)(v.z * sv);
      tile[(w4 + 3) * 130 + ci] = (bf16_t)(v.w * sv);
    }
    __syncthreads();
#pragma unroll
    for (int it = 0; it < 4; ++it) {
      int i = tid + it * 256;       // < 1024
      int w = i >> 4, cg = i & 15;  // 8 ci per chunk
      const uint32_t* tp = (const uint32_t*)&tile[w * 130 + (cg << 3)];
      uint4 v = { tp[0], tp[1], tp[2], tp[3] };
      *(uint4*)&xp[((size_t)(b * 66 + h + 1) * 66 + (w + 1)) * 512 + c0 + (cg << 3)] = v;
    }
  }
}

// Implicit-GEMM conv: D[(b,h,w)][co] = sum_{tap,ci} x_pad * w_t, scaled by d[b][co].
// 128 pixels (2 rows) x 128 co per block, 4 waves (2x2), 16x16x32 bf16 MFMA, BK=32.
// Block swizzle: xcd = blk&7 owns a contiguous 64-mb slab (2 images); nb innermost
// so the 4 A-sharing siblings are co-resident on one XCD (L2 A-reuse).
// LDS XOR bank-swizzle: phys 16B-group = logical_group ^ (row&3) (kills the 8-way
// ds_read_b128 conflict; source-side swizzle keeps global_load_lds layout legal).
__global__ __launch_bounds__(256) void conv_kernel(
    const bf16_t* __restrict__ xp, const bf16_t* __restrict__ w_t,
    const float* __restrict__ d, float* __restrict__ out) {
  __shared__ __align__(16) bf16_t smem[8192];   // As[128][32] | Bs[128][32]
  const int tid = threadIdx.x, lane = tid & 63;
  const int g = blockIdx.x;
  const int xcd = g & 7;
  const int slot = g >> 3;            // 0..255
  const int mb = (xcd << 6) + (slot >> 2);   // 0..511, contiguous slab per XCD
  const int nb = slot & 3;
  const int b = mb >> 5;
  const int h0 = (mb & 31) << 1;
  const int n0 = nb << 7;
  const int wv = tid >> 6, wm = wv >> 1, wn = wv & 1;
  const int quad = lane >> 4, lr = lane & 15;

  f32x4 acc[4][4];
#pragma unroll
  for (int i = 0; i < 4; ++i)
#pragma unroll
    for (int j = 0; j < 4; ++j) acc[i][j] = (f32x4){0.f, 0.f, 0.f, 0.f};

  for (int t = 0; t < 9; ++t) {
    const int kh = t / 3, kw = t % 3;
    for (int ci0 = 0; ci0 < 512; ci0 += 32) {
      __syncthreads();
      // stage A: 128 pixels x 32 ci (8 KB); source-group XOR-swizzled by pix&3
#pragma unroll
      for (int it = 0; it < 2; ++it) {
        int i = tid + (it << 8);          // [0,512)
        int pix = i >> 2;                 // [0,128)
        int kk = (((i & 3) ^ (pix & 3)) << 3);   // swizzled 8-elem ci group
        int hp = h0 + (pix >> 6) + kh;    // [0,66)
        int wp = (pix & 63) + kw;         // [0,66)
        const bf16_t* gp = xp + (((size_t)(b * 66 + hp) * 66 + wp) << 9) + ci0 + kk;
        async_ld16(gp, &smem[(i & ~63) << 3]);
      }
      // stage B: 128 co x 32 ci (8 KB); same swizzle by n&3
#pragma unroll
      for (int it = 0; it < 2; ++it) {
        int i = tid + (it << 8);
        int n = i >> 2;
        int kk = (((i & 3) ^ (n & 3)) << 3);
        const bf16_t* gp = w_t + (((size_t)((t << 9) + n0 + n)) << 9) + ci0 + kk;
        async_ld16(gp, &smem[4096 + ((i & ~63) << 3)]);
      }
      __syncthreads();
      bf16x8 af[4], bfr[4];
      const int sw = ((quad ^ (lr & 3)) << 3);   // un-swizzle on read
#pragma unroll
      for (int mt = 0; mt < 4; ++mt)
        af[mt] = *(const bf16x8*)&smem[(((wm << 6) + (mt << 4) + lr) << 5) + sw];
#pragma unroll
      for (int nt = 0; nt < 4; ++nt)
        bfr[nt] = *(const bf16x8*)&smem[4096 + (((wn << 6) + (nt << 4) + lr) << 5) + sw];
#pragma unroll
      for (int mt = 0; mt < 4; ++mt)
#pragma unroll
        for (int nt = 0; nt < 4; ++nt)
          acc[mt][nt] = __builtin_amdgcn_mfma_f32_16x16x32_bf16(af[mt], bfr[nt], acc[mt][nt], 0, 0, 0);
    }
  }

  // epilogue: out[b][co][h][w] = acc * d[b][co]
#pragma unroll
  for (int nt = 0; nt < 4; ++nt) {
    const int n = n0 + (wn << 6) + (nt << 4) + lr;
    const float dv = d[(b << 9) + n];
#pragma unroll
    for (int mt = 0; mt < 4; ++mt) {
#pragma unroll
      for (int r = 0; r < 4; ++r) {
        int m = (wm << 6) + (mt << 4) + (quad << 2) + r;   // pixel in tile
        int h = h0 + (m >> 6), w = m & 63;
        out[((size_t)((b << 9) + n) << 12) + (h << 6) + w] = acc[mt][nt][r] * dv;
      }
    }
  }
}

extern "C" void kernel_launch(void* const* d_in, const int* in_sizes, int n_in,
                              void* d_out, int out_size, void* d_ws, size_t ws_size,
                              hipStream_t stream) {
  const float* x      = (const float*)d_in[0];   // [16,512,64,64]
  const float* w      = (const float*)d_in[1];   // [16,512]
  const float* weight = (const float*)d_in[2];   // [512,512,3,3]
  const float* aw     = (const float*)d_in[3];   // [512,512]
  const float* ab     = (const float*)d_in[4];   // [512]
  float* out = (float*)d_out;

  char* ws = (char*)d_ws;
  const size_t XP_BYTES  = (size_t)16 * 66 * 66 * 512 * 2;  // 71,368,704
  const size_t WT_BYTES  = (size_t)9 * 512 * 512 * 2;       //  4,718,592
  bf16_t* xp   = (bf16_t*)ws;
  bf16_t* w_t  = (bf16_t*)(ws + XP_BYTES);
  float*  s    = (float*)(ws + XP_BYTES + WT_BYTES);
  float*  wsq  = (float*)(ws + XP_BYTES + WT_BYTES + 32768);
  float*  dbuf = (float*)(ws + XP_BYTES + WT_BYTES + 32768 + 1048576);

  halo_kernel<<<1040, 256, 0, stream>>>(xp);
  s_kernel<<<8192, 64, 0, stream>>>(w, aw, ab, s);
  prep_w_kernel<<<1024, 256, 0, stream>>>(weight, wsq, w_t);
  d_kernel<<<8192, 64, 0, stream>>>(wsq, s, dbuf);
  xmod_kernel<<<1024, 256, 0, stream>>>(x, s, xp);
  conv_kernel<<<2048, 256, 0, stream>>>(xp, w_t, dbuf, out);
}

// Round 3
// 533.685 us; speedup vs baseline: 1.2058x; 1.1327x over previous
//
#include <hip/hip_runtime.h>
#include <cstdint>

typedef __bf16 bf16_t;
typedef __attribute__((ext_vector_type(8))) __bf16 bf16x8;
typedef __attribute__((ext_vector_type(4))) float f32x4;

#define MC_EPS 1e-8f

__device__ __forceinline__ void async_ld16(const bf16_t* g, bf16_t* l) {
  __builtin_amdgcn_global_load_lds(
      (const __attribute__((address_space(1))) void*)g,
      (__attribute__((address_space(3))) void*)l, 16, 0, 0);
}

// s[b][ci] = dot(w[b,:], affine_w[ci,:]) + affine_b[ci] + 1
// one block per ci; 256 threads = 16 b-groups x 16 partial lanes
__global__ void s_kernel(const float* __restrict__ w, const float* __restrict__ aw,
                         const float* __restrict__ ab, float* __restrict__ s) {
  int ci = blockIdx.x, tid = threadIdx.x;
  int b = tid >> 4, part = tid & 15;
  const float* ar = aw + (ci << 9);
  const float* wr = w + (b << 9);
  float acc = 0.f;
  for (int j = part; j < 512; j += 16) acc += wr[j] * ar[j];
  for (int off = 8; off; off >>= 1) acc += __shfl_down(acc, off, 64);
  if (part == 0) s[(b << 9) + ci] = acc + ab[ci] + 1.0f;
}

// fused: wsq[co][ci] = sum_t w^2 ; w_t[t][co][ci] = bf16(w)  (one pass over weight)
__global__ void prep_w_kernel(const float* __restrict__ wgt, float* __restrict__ wsq,
                              bf16_t* __restrict__ w_t) {
  int idx = blockIdx.x * 256 + threadIdx.x;  // co*512+ci, < 262144
  const float* p = wgt + (size_t)idx * 9;
  float v[9];
  float a = 0.f;
#pragma unroll
  for (int j = 0; j < 9; ++j) { v[j] = p[j]; a += v[j] * v[j]; }
  wsq[idx] = a;
#pragma unroll
  for (int j = 0; j < 9; ++j) w_t[((size_t)j << 18) + idx] = (bf16_t)v[j];
}

// d[b][co] = rsqrt(sum_ci wsq[co][ci] * s[b][ci]^2 + eps); one block per co
__global__ void d_kernel(const float* __restrict__ wsq, const float* __restrict__ s,
                         float* __restrict__ d) {
  int co = blockIdx.x, tid = threadIdx.x;
  int b = tid >> 4, part = tid & 15;
  const float* wr = wsq + (co << 9);
  const float* sr = s + (b << 9);
  float acc = 0.f;
  for (int j = part; j < 512; j += 16) { float sv = sr[j]; acc += wr[j] * sv * sv; }
  for (int off = 8; off; off >>= 1) acc += __shfl_down(acc, off, 64);
  if (part == 0) d[(b << 9) + co] = rsqrtf(acc + MC_EPS);
}

// zero only the 1-px halo border of x_pad (4.3 MB instead of 71 MB memset)
__global__ void halo_kernel(bf16_t* __restrict__ xp) {
  int gid = blockIdx.x * 256 + threadIdx.x;  // 16*260*64 = 266240 threads
  if (gid >= 16 * 260 * 64) return;
  int cg = gid & 63;
  int p = (gid >> 6) % 260;
  int b = (gid >> 6) / 260;
  int h, w;
  if (p < 66)       { h = 0;       w = p; }
  else if (p < 132) { h = 65;      w = p - 66; }
  else if (p < 196) { h = p - 131; w = 0; }
  else              { h = p - 195; w = 65; }
  uint4 z = {0u, 0u, 0u, 0u};
  *(uint4*)&xp[((size_t)(b * 66 + h) * 66 + w) * 512 + (cg << 3)] = z;
}

// x_pad[b][h+1][w+1][ci] = bf16(x[b][ci][h][w] * s[b][ci])  (NHWC, 1-px halo)
__global__ void xmod_kernel(const float* __restrict__ x, const float* __restrict__ s,
                            bf16_t* __restrict__ xp) {
  int b = blockIdx.x >> 6, h = blockIdx.x & 63;
  int tid = threadIdx.x;
  __shared__ __align__(16) bf16_t tile[64 * 130];
  for (int c0 = 0; c0 < 512; c0 += 128) {
    if (c0) __syncthreads();
    int w4 = (tid & 15) << 2;   // 0..60
    int cl = tid >> 4;          // 0..15
#pragma unroll
    for (int r = 0; r < 8; ++r) {
      int ci = cl + (r << 4);   // 0..127
      const float4 v = *(const float4*)&x[(size_t)(((b << 9) + c0 + ci) << 12) + (h << 6) + w4];
      float sv = s[(b << 9) + c0 + ci];
      tile[(w4 + 0) * 130 + ci] = (bf16_t)(v.x * sv);
      tile[(w4 + 1) * 130 + ci] = (bf16_t)(v.y * sv);
      tile[(w4 + 2) * 130 + ci] = (bf16_t)(v.z * sv);
      tile[(w4 + 3) * 130 + ci] = (bf16_t)(v.w * sv);
    }
    __syncthreads();
#pragma unroll
    for (int it = 0; it < 4; ++it) {
      int i = tid + it * 256;       // < 1024
      int w = i >> 4, cg = i & 15;  // 8 ci per chunk
      const uint32_t* tp = (const uint32_t*)&tile[w * 130 + (cg << 3)];
      uint4 v = { tp[0], tp[1], tp[2], tp[3] };
      *(uint4*)&xp[((size_t)(b * 66 + h + 1) * 66 + (w + 1)) * 512 + c0 + (cg << 3)] = v;
    }
  }
}

// Implicit-GEMM conv: D[(b,h,w)][co] = sum_{tap,ci} x_pad * w_t, scaled by d[b][co].
// 128 pixels x 128 co per block, 4 waves (2x2), 16x16x32 bf16 MFMA, BK=64 (72 K-iters,
// half the barrier drains of BK=32). XCD swizzle: blk&7 -> contiguous 64-mb slab, nb
// innermost (A-sharing siblings co-resident -> L2 reuse; R2: FETCH 1.19GB->106MB).
// 128B row stride needs XOR swizzle phys_group = group ^ (row&7): without it all 16
// lr lanes of a quad hit one 4-bank group (16-way); with it 8 lanes/group = b128 min.
__global__ __launch_bounds__(256) void conv_kernel(
    const bf16_t* __restrict__ xp, const bf16_t* __restrict__ w_t,
    const float* __restrict__ d, float* __restrict__ out) {
  __shared__ __align__(16) bf16_t smem[16384];   // As[128][64] | Bs[128][64]
  const int tid = threadIdx.x, lane = tid & 63;
  const int g = blockIdx.x;
  const int xcd = g & 7;
  const int slot = g >> 3;            // 0..255
  const int mb = (xcd << 6) + (slot >> 2);   // 0..511, contiguous slab per XCD
  const int nb = slot & 3;
  const int b = mb >> 5;
  const int h0 = (mb & 31) << 1;
  const int n0 = nb << 7;
  const int wv = tid >> 6, wm = wv >> 1, wn = wv & 1;
  const int quad = lane >> 4, lr = lane & 15;

  f32x4 acc[4][4];
#pragma unroll
  for (int i = 0; i < 4; ++i)
#pragma unroll
    for (int j = 0; j < 4; ++j) acc[i][j] = (f32x4){0.f, 0.f, 0.f, 0.f};

  for (int t = 0; t < 9; ++t) {
    const int kh = t / 3, kw = t % 3;
    for (int ci0 = 0; ci0 < 512; ci0 += 64) {
      __syncthreads();
      // stage A: 128 pixels x 64 ci (16 KB); source-group XOR-swizzled by pix&7
#pragma unroll
      for (int it = 0; it < 4; ++it) {
        int i = tid + (it << 8);          // [0,1024)
        int pix = i >> 3;                 // [0,128)
        int kk = (((i & 7) ^ (pix & 7)) << 3);   // swizzled 8-elem ci group
        int hp = h0 + (pix >> 6) + kh;    // [0,66)
        int wp = (pix & 63) + kw;         // [0,66)
        const bf16_t* gp = xp + (((size_t)(b * 66 + hp) * 66 + wp) << 9) + ci0 + kk;
        async_ld16(gp, &smem[(i & ~63) << 3]);
      }
      // stage B: 128 co x 64 ci (16 KB); same swizzle by n&7
#pragma unroll
      for (int it = 0; it < 4; ++it) {
        int i = tid + (it << 8);
        int n = i >> 3;
        int kk = (((i & 7) ^ (n & 7)) << 3);
        const bf16_t* gp = w_t + (((size_t)((t << 9) + n0 + n)) << 9) + ci0 + kk;
        async_ld16(gp, &smem[8192 + ((i & ~63) << 3)]);
      }
      __syncthreads();
#pragma unroll
      for (int s = 0; s < 2; ++s) {
        bf16x8 af[4], bfr[4];
        const int phys = (((s << 2) | quad) ^ (lr & 7)) << 3;
#pragma unroll
        for (int mt = 0; mt < 4; ++mt)
          af[mt] = *(const bf16x8*)&smem[(((wm << 6) + (mt << 4) + lr) << 6) + phys];
#pragma unroll
        for (int nt = 0; nt < 4; ++nt)
          bfr[nt] = *(const bf16x8*)&smem[8192 + (((wn << 6) + (nt << 4) + lr) << 6) + phys];
#pragma unroll
        for (int mt = 0; mt < 4; ++mt)
#pragma unroll
          for (int nt = 0; nt < 4; ++nt)
            acc[mt][nt] = __builtin_amdgcn_mfma_f32_16x16x32_bf16(af[mt], bfr[nt], acc[mt][nt], 0, 0, 0);
      }
    }
  }

  // epilogue: out[b][co][h][w] = acc * d[b][co]
#pragma unroll
  for (int nt = 0; nt < 4; ++nt) {
    const int n = n0 + (wn << 6) + (nt << 4) + lr;
    const float dv = d[(b << 9) + n];
#pragma unroll
    for (int mt = 0; mt < 4; ++mt) {
#pragma unroll
      for (int r = 0; r < 4; ++r) {
        int m = (wm << 6) + (mt << 4) + (quad << 2) + r;   // pixel in tile
        int h = h0 + (m >> 6), w = m & 63;
        out[((size_t)((b << 9) + n) << 12) + (h << 6) + w] = acc[mt][nt][r] * dv;
      }
    }
  }
}

extern "C" void kernel_launch(void* const* d_in, const int* in_sizes, int n_in,
                              void* d_out, int out_size, void* d_ws, size_t ws_size,
                              hipStream_t stream) {
  const float* x      = (const float*)d_in[0];   // [16,512,64,64]
  const float* w      = (const float*)d_in[1];   // [16,512]
  const float* weight = (const float*)d_in[2];   // [512,512,3,3]
  const float* aw     = (const float*)d_in[3];   // [512,512]
  const float* ab     = (const float*)d_in[4];   // [512]
  float* out = (float*)d_out;

  char* ws = (char*)d_ws;
  const size_t XP_BYTES  = (size_t)16 * 66 * 66 * 512 * 2;  // 71,368,704
  const size_t WT_BYTES  = (size_t)9 * 512 * 512 * 2;       //  4,718,592
  bf16_t* xp   = (bf16_t*)ws;
  bf16_t* w_t  = (bf16_t*)(ws + XP_BYTES);
  float*  s    = (float*)(ws + XP_BYTES + WT_BYTES);
  float*  wsq  = (float*)(ws + XP_BYTES + WT_BYTES + 32768);
  float*  dbuf = (float*)(ws + XP_BYTES + WT_BYTES + 32768 + 1048576);

  halo_kernel<<<1040, 256, 0, stream>>>(xp);
  s_kernel<<<512, 256, 0, stream>>>(w, aw, ab, s);
  prep_w_kernel<<<1024, 256, 0, stream>>>(weight, wsq, w_t);
  d_kernel<<<512, 256, 0, stream>>>(wsq, s, dbuf);
  xmod_kernel<<<1024, 256, 0, stream>>>(x, s, xp);
  conv_kernel<<<2048, 256, 0, stream>>>(xp, w_t, dbuf, out);
}